// Round 2
// baseline (278.177 us; speedup 1.0000x reference)
//
#include <hip/hip_runtime.h>
#include <hip/hip_bf16.h>
#include <cstdint>

#define N_RNA 4000
#define N_DIS 2000
#define NNODE 6016
#define NFDIM 128
#define RDIM 64
#define NE 300000
#define NET (NE + NNODE)
#define NPAIR 500000

// ---------------- CSR build ----------------
__global__ void count_edges(const int* __restrict__ adj, int* __restrict__ cnt) {
    int k = blockIdx.x * blockDim.x + threadIdx.x;
    if (k >= NET) return;
    int dst = (k < NE) ? adj[NE + k] : (k - NE);
    atomicAdd(&cnt[dst], 1);
}

__global__ __launch_bounds__(256) void scan_counts(const int* __restrict__ cnt,
                                                   int* __restrict__ offs) {
    __shared__ int part[256];
    const int C = 24;  // 256*24 = 6144 >= 6016
    int t = threadIdx.x;
    int base = t * C;
    int loc[C];
    int sum = 0;
#pragma unroll
    for (int i = 0; i < C; i++) {
        int idx = base + i;
        int v = (idx < NNODE) ? cnt[idx] : 0;
        loc[i] = sum;  // exclusive within chunk
        sum += v;
    }
    part[t] = sum;
    __syncthreads();
    for (int off = 1; off < 256; off <<= 1) {
        int v = (t >= off) ? part[t - off] : 0;
        __syncthreads();
        part[t] += v;
        __syncthreads();
    }
    int ebase = part[t] - sum;
#pragma unroll
    for (int i = 0; i < C; i++) {
        int idx = base + i;
        if (idx < NNODE) offs[idx] = ebase + loc[i];
    }
    if (t == 255) offs[NNODE] = part[255];
}

__global__ void fill_csr(const int* __restrict__ adj, const int* __restrict__ offs,
                         int* __restrict__ cur, int* __restrict__ srcs) {
    int k = blockIdx.x * blockDim.x + threadIdx.x;
    if (k >= NET) return;
    int src, dst;
    if (k < NE) { src = adj[k]; dst = adj[NE + k]; }
    else        { src = k - NE; dst = k - NE; }
    int pos = atomicAdd(&cur[dst], 1);
    srcs[offs[dst] + pos] = src;
}

// ---------------- GAT projection: h = x @ W, plus attention scores ----------------
template <int NF>
__global__ __launch_bounds__(64) void proj_kernel(const float* __restrict__ x,
                                                  const float* __restrict__ W,
                                                  const float* __restrict__ a_s,
                                                  const float* __restrict__ a_d,
                                                  float* __restrict__ h,
                                                  float* __restrict__ ssrc,
                                                  float* __restrict__ sdst) {
    __shared__ float xr[NF];
    int node = blockIdx.x;
    int t = threadIdx.x;
    {
        const float* xp = x + (size_t)node * NF;
        for (int i = t; i < NF; i += 64) xr[i] = xp[i];
    }
    __syncthreads();
    float acc = 0.f;
#pragma unroll 8
    for (int k = 0; k < NF; k++) acc = fmaf(xr[k], W[k * RDIM + t], acc);
    h[(size_t)node * RDIM + t] = acc;
    float vs = acc * a_s[t];
    float vd = acc * a_d[t];
#pragma unroll
    for (int off = 32; off; off >>= 1) {
        vs += __shfl_down(vs, off);
        vd += __shfl_down(vd, off);
    }
    if (t == 0) { ssrc[node] = vs; sdst[node] = vd; }
}

// ---------------- GAT aggregation (softmax over incoming edges) ----------------
__global__ __launch_bounds__(64) void agg_kernel(const float* __restrict__ h,
                                                 const float* __restrict__ ssrc,
                                                 const float* __restrict__ sdst,
                                                 const int* __restrict__ offs,
                                                 const int* __restrict__ srcs,
                                                 const float* __restrict__ bias,
                                                 float* __restrict__ out) {
    int node = blockIdx.x;
    int t = threadIdx.x;
    int beg = offs[node], end = offs[node + 1];
    float sd = sdst[node];
    // pass A: segment max (lanes over edges)
    float m = -1e30f;
    for (int i = beg + t; i < end; i += 64) {
        float v = ssrc[srcs[i]] + sd;
        v = v > 0.f ? v : 0.2f * v;
        m = fmaxf(m, v);
    }
#pragma unroll
    for (int off = 32; off; off >>= 1) m = fmaxf(m, __shfl_xor(m, off));
    // pass B: exp/sum/accumulate (lanes over feature dims, serial over edges)
    float acc = 0.f, den = 0.f;
    for (int i = beg; i < end; i++) {
        int s = srcs[i];
        float v = ssrc[s] + sd;
        v = v > 0.f ? v : 0.2f * v;
        float ex = __expf(v - m);
        den += ex;
        acc = fmaf(ex, h[(size_t)s * RDIM + t], acc);
    }
    out[(size_t)node * RDIM + t] = acc / den + bias[t];
}

// ---------------- pairwise MLP ----------------
__global__ __launch_bounds__(256) void mlp_kernel(const float* __restrict__ h,
                                                  const int* __restrict__ coo,
                                                  const float* __restrict__ w1, const float* __restrict__ b1,
                                                  const float* __restrict__ w2, const float* __restrict__ b2,
                                                  const float* __restrict__ w3, const float* __restrict__ b3,
                                                  const float* __restrict__ w4, const float* __restrict__ b4,
                                                  const float* __restrict__ w5, const float* __restrict__ b5,
                                                  const float* __restrict__ w6, const float* __restrict__ b6,
                                                  float* __restrict__ out) {
    int p = blockIdx.x * 256 + threadIdx.x;
    if (p >= NPAIR) return;
    int r = coo[2 * p];
    int d = coo[2 * p + 1];
    const float* x1 = h + (size_t)r * RDIM;
    const float* x2 = h + (size_t)(N_RNA + d) * RDIM;

    float a1[64];
#pragma unroll
    for (int j = 0; j < 64; j++) a1[j] = b1[j];
    {
        float z[64];
#pragma unroll
        for (int k = 0; k < 64; k++) z[k] = x1[k];
#pragma unroll
        for (int k = 0; k < 64; k++) {
            float zk = z[k];
#pragma unroll
            for (int j = 0; j < 64; j++) a1[j] = fmaf(zk, w1[k * 64 + j], a1[j]);
        }
#pragma unroll
        for (int k = 0; k < 64; k++) z[k] = x2[k];
#pragma unroll
        for (int k = 0; k < 64; k++) {
            float zk = z[k];
#pragma unroll
            for (int j = 0; j < 64; j++) a1[j] = fmaf(zk, w1[(64 + k) * 64 + j], a1[j]);
        }
    }
#pragma unroll
    for (int j = 0; j < 64; j++) a1[j] = fmaxf(a1[j], 0.f);

    float a2[32];
#pragma unroll
    for (int j = 0; j < 32; j++) a2[j] = b2[j];
#pragma unroll
    for (int k = 0; k < 64; k++) {
        float zk = a1[k];
#pragma unroll
        for (int j = 0; j < 32; j++) a2[j] = fmaf(zk, w2[k * 32 + j], a2[j]);
    }
#pragma unroll
    for (int j = 0; j < 32; j++) a2[j] = fmaxf(a2[j], 0.f);

    float a3[32];
#pragma unroll
    for (int j = 0; j < 32; j++) a3[j] = b3[j];
#pragma unroll
    for (int k = 0; k < 32; k++) {
        float zk = a2[k];
#pragma unroll
        for (int j = 0; j < 32; j++) a3[j] = fmaf(zk, w3[k * 32 + j], a3[j]);
    }
#pragma unroll
    for (int j = 0; j < 32; j++) a3[j] = fmaxf(a3[j], 0.f);

    float a4[16];
#pragma unroll
    for (int j = 0; j < 16; j++) a4[j] = b4[j];
#pragma unroll
    for (int k = 0; k < 32; k++) {
        float zk = a3[k];
#pragma unroll
        for (int j = 0; j < 16; j++) a4[j] = fmaf(zk, w4[k * 16 + j], a4[j]);
    }
#pragma unroll
    for (int j = 0; j < 16; j++) a4[j] = fmaxf(a4[j], 0.f);

    float a5[8];
#pragma unroll
    for (int j = 0; j < 8; j++) a5[j] = b5[j];
#pragma unroll
    for (int k = 0; k < 16; k++) {
        float zk = a4[k];
#pragma unroll
        for (int j = 0; j < 8; j++) a5[j] = fmaf(zk, w5[k * 8 + j], a5[j]);
    }
#pragma unroll
    for (int j = 0; j < 8; j++) a5[j] = fmaxf(a5[j], 0.f);

    float logit = b6[0];
#pragma unroll
    for (int k = 0; k < 8; k++) logit = fmaf(a5[k], w6[k], logit);

    float sig = 1.f / (1.f + __expf(-logit));
    out[p] = sig;
}

// ---------------- launch ----------------
extern "C" void kernel_launch(void* const* d_in, const int* in_sizes, int n_in,
                              void* d_out, int out_size, void* d_ws, size_t ws_size,
                              hipStream_t stream) {
    const float* x    = (const float*)d_in[0];
    const int*   adj  = (const int*)d_in[1];
    const int*   coo  = (const int*)d_in[2];
    const float* gw0  = (const float*)d_in[3];
    const float* gas0 = (const float*)d_in[4];
    const float* gad0 = (const float*)d_in[5];
    const float* gb0  = (const float*)d_in[6];
    const float* gw1  = (const float*)d_in[7];
    const float* gas1 = (const float*)d_in[8];
    const float* gad1 = (const float*)d_in[9];
    const float* gb1  = (const float*)d_in[10];

    char* ws = (char*)d_ws;
    size_t o = 0;
    auto take = [&](size_t bytes) -> void* {
        void* p = ws + o;
        o = (o + bytes + 255) & ~(size_t)255;
        return p;
    };
    float* hP   = (float*)take((size_t)NNODE * RDIM * 4);
    float* hO1  = (float*)take((size_t)NNODE * RDIM * 4);
    float* hO2  = (float*)take((size_t)NNODE * RDIM * 4);
    float* ssrc = (float*)take((size_t)NNODE * 4);
    float* sdst = (float*)take((size_t)NNODE * 4);
    int*   offs = (int*)take((size_t)(NNODE + 1) * 4);
    int*   cnt  = (int*)take((size_t)NNODE * 4);
    int*   cur  = (int*)take((size_t)NNODE * 4);
    int*   srcs = (int*)take((size_t)NET * 4);

    hipMemsetAsync(cnt, 0, (size_t)NNODE * 4, stream);
    hipMemsetAsync(cur, 0, (size_t)NNODE * 4, stream);

    count_edges<<<(NET + 255) / 256, 256, 0, stream>>>(adj, cnt);
    scan_counts<<<1, 256, 0, stream>>>(cnt, offs);
    fill_csr<<<(NET + 255) / 256, 256, 0, stream>>>(adj, offs, cur, srcs);

    // GAT layer 1
    proj_kernel<NFDIM><<<NNODE, 64, 0, stream>>>(x, gw0, gas0, gad0, hP, ssrc, sdst);
    agg_kernel<<<NNODE, 64, 0, stream>>>(hP, ssrc, sdst, offs, srcs, gb0, hO1);
    // GAT layer 2
    proj_kernel<RDIM><<<NNODE, 64, 0, stream>>>(hO1, gw1, gas1, gad1, hP, ssrc, sdst);
    agg_kernel<<<NNODE, 64, 0, stream>>>(hP, ssrc, sdst, offs, srcs, gb1, hO2);
    // pairwise MLP
    mlp_kernel<<<(NPAIR + 255) / 256, 256, 0, stream>>>(
        hO2, coo,
        (const float*)d_in[11], (const float*)d_in[12],
        (const float*)d_in[13], (const float*)d_in[14],
        (const float*)d_in[15], (const float*)d_in[16],
        (const float*)d_in[17], (const float*)d_in[18],
        (const float*)d_in[19], (const float*)d_in[20],
        (const float*)d_in[21], (const float*)d_in[22],
        (float*)d_out);
}

// Round 3
// 187.870 us; speedup vs baseline: 1.4807x; 1.4807x over previous
//
#include <hip/hip_runtime.h>
#include <hip/hip_bf16.h>
#include <cstdint>

#define N_RNA 4000
#define N_DIS 2000
#define NNODE 6016
#define NFDIM 128
#define RDIM 64
#define NE 300000
#define NET (NE + NNODE)
#define NPAIR 500000

// ---------------- CSR build ----------------
__global__ void count_edges(const int* __restrict__ adj, int* __restrict__ cnt) {
    int k = blockIdx.x * blockDim.x + threadIdx.x;
    if (k >= NET) return;
    int dst = (k < NE) ? adj[NE + k] : (k - NE);
    atomicAdd(&cnt[dst], 1);
}

__global__ __launch_bounds__(256) void scan_counts(const int* __restrict__ cnt,
                                                   int* __restrict__ offs) {
    __shared__ int part[256];
    const int C = 24;  // 256*24 = 6144 >= 6016
    int t = threadIdx.x;
    int base = t * C;
    int loc[C];
    int sum = 0;
#pragma unroll
    for (int i = 0; i < C; i++) {
        int idx = base + i;
        int v = (idx < NNODE) ? cnt[idx] : 0;
        loc[i] = sum;
        sum += v;
    }
    part[t] = sum;
    __syncthreads();
    for (int off = 1; off < 256; off <<= 1) {
        int v = (t >= off) ? part[t - off] : 0;
        __syncthreads();
        part[t] += v;
        __syncthreads();
    }
    int ebase = part[t] - sum;
#pragma unroll
    for (int i = 0; i < C; i++) {
        int idx = base + i;
        if (idx < NNODE) offs[idx] = ebase + loc[i];
    }
    if (t == 255) offs[NNODE] = part[255];
}

__global__ void fill_csr(const int* __restrict__ adj, const int* __restrict__ offs,
                         int* __restrict__ cur, int* __restrict__ srcs) {
    int k = blockIdx.x * blockDim.x + threadIdx.x;
    if (k >= NET) return;
    int src, dst;
    if (k < NE) { src = adj[k]; dst = adj[NE + k]; }
    else        { src = k - NE; dst = k - NE; }
    int pos = atomicAdd(&cur[dst], 1);
    srcs[offs[dst] + pos] = src;
}

// ---------------- GAT projection: h = x @ W, plus attention scores ----------------
template <int NF>
__global__ __launch_bounds__(64) void proj_kernel(const float* __restrict__ x,
                                                  const float* __restrict__ W,
                                                  const float* __restrict__ a_s,
                                                  const float* __restrict__ a_d,
                                                  float* __restrict__ h,
                                                  float* __restrict__ ssrc,
                                                  float* __restrict__ sdst) {
    __shared__ float xr[NF];
    int node = blockIdx.x;
    int t = threadIdx.x;
    {
        const float* xp = x + (size_t)node * NF;
        for (int i = t; i < NF; i += 64) xr[i] = xp[i];
    }
    __syncthreads();
    float acc = 0.f;
#pragma unroll 8
    for (int k = 0; k < NF; k++) acc = fmaf(xr[k], W[k * RDIM + t], acc);
    h[(size_t)node * RDIM + t] = acc;
    float vs = acc * a_s[t];
    float vd = acc * a_d[t];
#pragma unroll
    for (int off = 32; off; off >>= 1) {
        vs += __shfl_down(vs, off);
        vd += __shfl_down(vd, off);
    }
    if (t == 0) { ssrc[node] = vs; sdst[node] = vd; }
}

// ---------------- GAT aggregation (softmax over incoming edges) ----------------
__global__ __launch_bounds__(64) void agg_kernel(const float* __restrict__ h,
                                                 const float* __restrict__ ssrc,
                                                 const float* __restrict__ sdst,
                                                 const int* __restrict__ offs,
                                                 const int* __restrict__ srcs,
                                                 const float* __restrict__ bias,
                                                 float* __restrict__ out) {
    int node = blockIdx.x;
    int t = threadIdx.x;
    int beg = offs[node], end = offs[node + 1];
    float sd = sdst[node];
    float m = -1e30f;
    for (int i = beg + t; i < end; i += 64) {
        float v = ssrc[srcs[i]] + sd;
        v = v > 0.f ? v : 0.2f * v;
        m = fmaxf(m, v);
    }
#pragma unroll
    for (int off = 32; off; off >>= 1) m = fmaxf(m, __shfl_xor(m, off));
    float acc = 0.f, den = 0.f;
    for (int i = beg; i < end; i++) {
        int s = srcs[i];
        float v = ssrc[s] + sd;
        v = v > 0.f ? v : 0.2f * v;
        float ex = __expf(v - m);
        den += ex;
        acc = fmaf(ex, h[(size_t)s * RDIM + t], acc);
    }
    out[(size_t)node * RDIM + t] = acc / den + bias[t];
}

// ---------------- pair-independent layer-1 precompute ----------------
// u1[r] = h[r] @ w1[0:64,:]  + b1   (r in [0,4000))
// u2[d] = h[4000+d] @ w1[64:128,:]  (d in [0,2000))
__global__ __launch_bounds__(64) void pair_pre_kernel(const float* __restrict__ h,
                                                      const float* __restrict__ w1,
                                                      const float* __restrict__ b1,
                                                      float* __restrict__ u1,
                                                      float* __restrict__ u2) {
    __shared__ float xr[64];
    int node = blockIdx.x;  // 0..5999
    int t = threadIdx.x;
    bool rna = node < N_RNA;
    xr[t] = h[(size_t)node * RDIM + t];
    __syncthreads();
    const float* w = rna ? w1 : (w1 + 64 * 64);
    float acc = rna ? b1[t] : 0.f;
#pragma unroll
    for (int k = 0; k < 64; k++) acc = fmaf(xr[k], w[k * 64 + t], acc);
    if (rna) u1[(size_t)node * 64 + t] = acc;
    else     u2[(size_t)(node - N_RNA) * 64 + t] = acc;
}

// ---------------- pairwise MLP (layers 2..6; layer 1 via u1+u2 gather) ----------------
__global__ __launch_bounds__(256) void mlp_kernel(const float* __restrict__ u1,
                                                  const float* __restrict__ u2,
                                                  const int* __restrict__ coo,
                                                  const float* __restrict__ w2, const float* __restrict__ b2,
                                                  const float* __restrict__ w3, const float* __restrict__ b3,
                                                  const float* __restrict__ w4, const float* __restrict__ b4,
                                                  const float* __restrict__ w5, const float* __restrict__ b5,
                                                  const float* __restrict__ w6, const float* __restrict__ b6,
                                                  float* __restrict__ out) {
    int p = blockIdx.x * 256 + threadIdx.x;
    if (p >= NPAIR) return;
    int r = coo[2 * p];
    int d = coo[2 * p + 1];
    const float4* p1 = (const float4*)(u1 + (size_t)r * 64);
    const float4* p2 = (const float4*)(u2 + (size_t)d * 64);

    float a1[64];
#pragma unroll
    for (int q = 0; q < 16; q++) {
        float4 v1 = p1[q];
        float4 v2 = p2[q];
        a1[4 * q + 0] = fmaxf(v1.x + v2.x, 0.f);
        a1[4 * q + 1] = fmaxf(v1.y + v2.y, 0.f);
        a1[4 * q + 2] = fmaxf(v1.z + v2.z, 0.f);
        a1[4 * q + 3] = fmaxf(v1.w + v2.w, 0.f);
    }

    float a2[32];
#pragma unroll
    for (int j = 0; j < 32; j++) a2[j] = b2[j];
#pragma unroll
    for (int k = 0; k < 64; k++) {
        float zk = a1[k];
#pragma unroll
        for (int j = 0; j < 32; j++) a2[j] = fmaf(zk, w2[k * 32 + j], a2[j]);
    }
#pragma unroll
    for (int j = 0; j < 32; j++) a2[j] = fmaxf(a2[j], 0.f);

    float a3[32];
#pragma unroll
    for (int j = 0; j < 32; j++) a3[j] = b3[j];
#pragma unroll
    for (int k = 0; k < 32; k++) {
        float zk = a2[k];
#pragma unroll
        for (int j = 0; j < 32; j++) a3[j] = fmaf(zk, w3[k * 32 + j], a3[j]);
    }
#pragma unroll
    for (int j = 0; j < 32; j++) a3[j] = fmaxf(a3[j], 0.f);

    float a4[16];
#pragma unroll
    for (int j = 0; j < 16; j++) a4[j] = b4[j];
#pragma unroll
    for (int k = 0; k < 32; k++) {
        float zk = a3[k];
#pragma unroll
        for (int j = 0; j < 16; j++) a4[j] = fmaf(zk, w4[k * 16 + j], a4[j]);
    }
#pragma unroll
    for (int j = 0; j < 16; j++) a4[j] = fmaxf(a4[j], 0.f);

    float a5[8];
#pragma unroll
    for (int j = 0; j < 8; j++) a5[j] = b5[j];
#pragma unroll
    for (int k = 0; k < 16; k++) {
        float zk = a4[k];
#pragma unroll
        for (int j = 0; j < 8; j++) a5[j] = fmaf(zk, w5[k * 8 + j], a5[j]);
    }
#pragma unroll
    for (int j = 0; j < 8; j++) a5[j] = fmaxf(a5[j], 0.f);

    float logit = b6[0];
#pragma unroll
    for (int k = 0; k < 8; k++) logit = fmaf(a5[k], w6[k], logit);

    float sig = 1.f / (1.f + __expf(-logit));
    out[p] = sig;
}

// ---------------- launch ----------------
extern "C" void kernel_launch(void* const* d_in, const int* in_sizes, int n_in,
                              void* d_out, int out_size, void* d_ws, size_t ws_size,
                              hipStream_t stream) {
    const float* x    = (const float*)d_in[0];
    const int*   adj  = (const int*)d_in[1];
    const int*   coo  = (const int*)d_in[2];
    const float* gw0  = (const float*)d_in[3];
    const float* gas0 = (const float*)d_in[4];
    const float* gad0 = (const float*)d_in[5];
    const float* gb0  = (const float*)d_in[6];
    const float* gw1  = (const float*)d_in[7];
    const float* gas1 = (const float*)d_in[8];
    const float* gad1 = (const float*)d_in[9];
    const float* gb1  = (const float*)d_in[10];

    char* ws = (char*)d_ws;
    size_t o = 0;
    auto take = [&](size_t bytes) -> void* {
        void* p = ws + o;
        o = (o + bytes + 255) & ~(size_t)255;
        return p;
    };
    float* hP   = (float*)take((size_t)NNODE * RDIM * 4);
    float* hO1  = (float*)take((size_t)NNODE * RDIM * 4);
    float* hO2  = (float*)take((size_t)NNODE * RDIM * 4);
    float* u1   = (float*)take((size_t)N_RNA * 64 * 4);
    float* u2   = (float*)take((size_t)N_DIS * 64 * 4);
    float* ssrc = (float*)take((size_t)NNODE * 4);
    float* sdst = (float*)take((size_t)NNODE * 4);
    int*   offs = (int*)take((size_t)(NNODE + 1) * 4);
    int*   cnt  = (int*)take((size_t)NNODE * 4);
    int*   cur  = (int*)take((size_t)NNODE * 4);
    int*   srcs = (int*)take((size_t)NET * 4);

    hipMemsetAsync(cnt, 0, (size_t)NNODE * 4, stream);
    hipMemsetAsync(cur, 0, (size_t)NNODE * 4, stream);

    count_edges<<<(NET + 255) / 256, 256, 0, stream>>>(adj, cnt);
    scan_counts<<<1, 256, 0, stream>>>(cnt, offs);
    fill_csr<<<(NET + 255) / 256, 256, 0, stream>>>(adj, offs, cur, srcs);

    // GAT layer 1
    proj_kernel<NFDIM><<<NNODE, 64, 0, stream>>>(x, gw0, gas0, gad0, hP, ssrc, sdst);
    agg_kernel<<<NNODE, 64, 0, stream>>>(hP, ssrc, sdst, offs, srcs, gb0, hO1);
    // GAT layer 2
    proj_kernel<RDIM><<<NNODE, 64, 0, stream>>>(hO1, gw1, gas1, gad1, hP, ssrc, sdst);
    agg_kernel<<<NNODE, 64, 0, stream>>>(hP, ssrc, sdst, offs, srcs, gb1, hO2);

    // layer-1 precompute: u1 (rna nodes, +b1 folded), u2 (dis nodes)
    pair_pre_kernel<<<N_RNA + N_DIS, 64, 0, stream>>>(
        hO2, (const float*)d_in[11], (const float*)d_in[12], u1, u2);

    // pairwise MLP, layers 2..6
    mlp_kernel<<<(NPAIR + 255) / 256, 256, 0, stream>>>(
        u1, u2, coo,
        (const float*)d_in[13], (const float*)d_in[14],
        (const float*)d_in[15], (const float*)d_in[16],
        (const float*)d_in[17], (const float*)d_in[18],
        (const float*)d_in[19], (const float*)d_in[20],
        (const float*)d_in[21], (const float*)d_in[22],
        (float*)d_out);
}

// Round 5
// 133.392 us; speedup vs baseline: 2.0854x; 1.4084x over previous
//
#include <hip/hip_runtime.h>
#include <cstdint>

#define N_RNA 4000
#define N_DIS 2000
#define NNODE 6016
#define NFDIM 128
#define RDIM 64
#define NE 300000
#define NET (NE + NNODE)
#define NPAIR 500000
#define NTILE (NPAIR / 16)  // 31250 exactly

typedef float vf4 __attribute__((ext_vector_type(4)));
typedef _Float16 f16x8 __attribute__((ext_vector_type(8)));
typedef _Float16 f16x2 __attribute__((ext_vector_type(2)));

union FragU {
    f16x8 f;
    f16x2 h[4];
    int   u[4];
};

__device__ __forceinline__ f16x2 pkrtz(float lo, float hi) {
    auto r = __builtin_amdgcn_cvt_pkrtz(lo, hi);
    return __builtin_bit_cast(f16x2, r);
}
__device__ __forceinline__ vf4 mfma16(const FragU& a, const FragU& b, vf4 c) {
    return __builtin_amdgcn_mfma_f32_16x16x32_f16(a.f, b.f, c, 0, 0, 0);
}

// Rebuild B-fragment (next layer's a^T) from two C/D acc tiles, in-register.
// Source: lane(col,g) holds acc0 -> features 4g+r, acc1 -> features 16+4g+r (post bias+relu).
// Target: lane(col,g) word j = features {8g+2j, 8g+2j+1} of pair col.
__device__ __forceinline__ FragU trans32(vf4 a0, vf4 a1, int col, int g) {
    FragU w;
    w.h[0] = pkrtz(a0[0], a0[1]);
    w.h[1] = pkrtz(a0[2], a0[3]);
    w.h[2] = pkrtz(a1[0], a1[1]);
    w.h[3] = pkrtz(a1[2], a1[3]);
    int addrA = (col + 16 * ((2 * g) & 3)) * 4;
    int addrB = (col + 16 * ((2 * g + 1) & 3)) * 4;
    int t0a = __builtin_amdgcn_ds_bpermute(addrA, w.u[0]);
    int t1a = __builtin_amdgcn_ds_bpermute(addrA, w.u[1]);
    int t2a = __builtin_amdgcn_ds_bpermute(addrA, w.u[2]);
    int t3a = __builtin_amdgcn_ds_bpermute(addrA, w.u[3]);
    int t0b = __builtin_amdgcn_ds_bpermute(addrB, w.u[0]);
    int t1b = __builtin_amdgcn_ds_bpermute(addrB, w.u[1]);
    int t2b = __builtin_amdgcn_ds_bpermute(addrB, w.u[2]);
    int t3b = __builtin_amdgcn_ds_bpermute(addrB, w.u[3]);
    bool hi = g >= 2;
    FragU B;
    B.u[0] = hi ? t2a : t0a;
    B.u[1] = hi ? t3a : t1a;
    B.u[2] = hi ? t2b : t0b;
    B.u[3] = hi ? t3b : t1b;
    return B;
}

// 16-feature source (single acc tile) -> K=32 fragment zero-padded for k>=16.
__device__ __forceinline__ FragU trans16(vf4 a, int col, int g) {
    int w0, w1;
    {
        f16x2 p0 = pkrtz(a[0], a[1]);
        f16x2 p1 = pkrtz(a[2], a[3]);
        FragU tmp; tmp.h[0] = p0; tmp.h[1] = p1;
        w0 = tmp.u[0]; w1 = tmp.u[1];
    }
    int addrA = (col + 16 * ((2 * g) & 3)) * 4;
    int addrB = (col + 16 * ((2 * g + 1) & 3)) * 4;
    int j0 = __builtin_amdgcn_ds_bpermute(addrA, w0);
    int j1 = __builtin_amdgcn_ds_bpermute(addrA, w1);
    int j2 = __builtin_amdgcn_ds_bpermute(addrB, w0);
    int j3 = __builtin_amdgcn_ds_bpermute(addrB, w1);
    bool lo2 = g < 2;
    FragU B;
    B.u[0] = lo2 ? j0 : 0;
    B.u[1] = lo2 ? j1 : 0;
    B.u[2] = lo2 ? j2 : 0;
    B.u[3] = lo2 ? j3 : 0;
    return B;
}

// ---------------- CSR build ----------------
__global__ void count_edges(const int* __restrict__ adj, int* __restrict__ cnt) {
    int k = blockIdx.x * blockDim.x + threadIdx.x;
    if (k >= NET) return;
    int dst = (k < NE) ? adj[NE + k] : (k - NE);
    atomicAdd(&cnt[dst], 1);
}

__global__ __launch_bounds__(256) void scan_counts(const int* __restrict__ cnt,
                                                   int* __restrict__ offs) {
    __shared__ int part[256];
    const int C = 24;  // 256*24 = 6144 >= 6016
    int t = threadIdx.x;
    int base = t * C;
    int loc[C];
    int sum = 0;
#pragma unroll
    for (int i = 0; i < C; i++) {
        int idx = base + i;
        int v = (idx < NNODE) ? cnt[idx] : 0;
        loc[i] = sum;
        sum += v;
    }
    part[t] = sum;
    __syncthreads();
    for (int off = 1; off < 256; off <<= 1) {
        int v = (t >= off) ? part[t - off] : 0;
        __syncthreads();
        part[t] += v;
        __syncthreads();
    }
    int ebase = part[t] - sum;
#pragma unroll
    for (int i = 0; i < C; i++) {
        int idx = base + i;
        if (idx < NNODE) offs[idx] = ebase + loc[i];
    }
    if (t == 255) offs[NNODE] = part[255];
}

__global__ void fill_csr(const int* __restrict__ adj, const int* __restrict__ offs,
                         int* __restrict__ cur, int* __restrict__ srcs) {
    int k = blockIdx.x * blockDim.x + threadIdx.x;
    if (k >= NET) return;
    int src, dst;
    if (k < NE) { src = adj[k]; dst = adj[NE + k]; }
    else        { src = k - NE; dst = k - NE; }
    int pos = atomicAdd(&cur[dst], 1);
    srcs[offs[dst] + pos] = src;
}

// ---------------- GAT projection: h = x @ W, plus attention scores ----------------
template <int NF>
__global__ __launch_bounds__(64) void proj_kernel(const float* __restrict__ x,
                                                  const float* __restrict__ W,
                                                  const float* __restrict__ a_s,
                                                  const float* __restrict__ a_d,
                                                  float* __restrict__ h,
                                                  float* __restrict__ ssrc,
                                                  float* __restrict__ sdst) {
    __shared__ float xr[NF];
    int node = blockIdx.x;
    int t = threadIdx.x;
    {
        const float* xp = x + (size_t)node * NF;
        for (int i = t; i < NF; i += 64) xr[i] = xp[i];
    }
    __syncthreads();
    float acc = 0.f;
#pragma unroll 8
    for (int k = 0; k < NF; k++) acc = fmaf(xr[k], W[k * RDIM + t], acc);
    h[(size_t)node * RDIM + t] = acc;
    float vs = acc * a_s[t];
    float vd = acc * a_d[t];
#pragma unroll
    for (int off = 32; off; off >>= 1) {
        vs += __shfl_down(vs, off);
        vd += __shfl_down(vd, off);
    }
    if (t == 0) { ssrc[node] = vs; sdst[node] = vd; }
}

// ---------------- GAT aggregation v2: 4 edge-groups x 16 lanes x float4 ----------------
__global__ __launch_bounds__(64) void agg_kernel(const float* __restrict__ h,
                                                 const float* __restrict__ ssrc,
                                                 const float* __restrict__ sdst,
                                                 const int* __restrict__ offs,
                                                 const int* __restrict__ srcs,
                                                 const float* __restrict__ bias,
                                                 float* __restrict__ out) {
    int node = blockIdx.x;
    int t = threadIdx.x;
    int beg = offs[node], end = offs[node + 1];
    float sd = sdst[node];
    // pass 1: segment max, 64 lanes over edges
    float m = -1e30f;
    for (int i = beg + t; i < end; i += 64) {
        float v = ssrc[srcs[i]] + sd;
        v = v > 0.f ? v : 0.2f * v;
        m = fmaxf(m, v);
    }
#pragma unroll
    for (int off = 32; off; off >>= 1) m = fmaxf(m, __shfl_xor(m, off));
    // pass 2: 4 edges in parallel; 16 lanes x float4 cover the 64 features
    int g = t >> 4, q = t & 15;
    float ax = 0.f, ay = 0.f, az = 0.f, aw = 0.f, den = 0.f;
    for (int i = beg + g; i < end; i += 4) {
        int s = srcs[i];
        float v = ssrc[s] + sd;
        v = v > 0.f ? v : 0.2f * v;
        float ex = __expf(v - m);
        den += ex;
        float4 hv = *(const float4*)(h + (size_t)s * 64 + q * 4);
        ax = fmaf(ex, hv.x, ax);
        ay = fmaf(ex, hv.y, ay);
        az = fmaf(ex, hv.z, az);
        aw = fmaf(ex, hv.w, aw);
    }
#pragma unroll
    for (int off = 16; off <= 32; off <<= 1) {
        ax += __shfl_xor(ax, off);
        ay += __shfl_xor(ay, off);
        az += __shfl_xor(az, off);
        aw += __shfl_xor(aw, off);
        den += __shfl_xor(den, off);
    }
    if (t < 16) {
        float inv = 1.f / den;
        float4 b4 = ((const float4*)bias)[q];
        float4 o;
        o.x = ax * inv + b4.x;
        o.y = ay * inv + b4.y;
        o.z = az * inv + b4.z;
        o.w = aw * inv + b4.w;
        *(float4*)(out + (size_t)node * 64 + q * 4) = o;
    }
}

// ---------------- pair-independent layer-1 precompute ----------------
__global__ __launch_bounds__(64) void pair_pre_kernel(const float* __restrict__ h,
                                                      const float* __restrict__ w1,
                                                      const float* __restrict__ b1,
                                                      float* __restrict__ u1,
                                                      float* __restrict__ u2) {
    __shared__ float xr[64];
    int node = blockIdx.x;
    int t = threadIdx.x;
    bool rna = node < N_RNA;
    xr[t] = h[(size_t)node * RDIM + t];
    __syncthreads();
    const float* w = rna ? w1 : (w1 + 64 * 64);
    float acc = rna ? b1[t] : 0.f;
#pragma unroll
    for (int k = 0; k < 64; k++) acc = fmaf(xr[k], w[k * 64 + t], acc);
    if (rna) u1[(size_t)node * 64 + t] = acc;
    else     u2[(size_t)(node - N_RNA) * 64 + t] = acc;
}

// ---------------- pairwise MLP: f16 MFMA transposed chain ----------------
// Per wave: 16 pairs. D^T = W^T * a^T every layer; pairs live in the col dim.
__global__ __launch_bounds__(256) void mlp_mfma_kernel(
    const float* __restrict__ u1, const float* __restrict__ u2,
    const int* __restrict__ coo,
    const float* __restrict__ w2, const float* __restrict__ b2,
    const float* __restrict__ w3, const float* __restrict__ b3,
    const float* __restrict__ w4, const float* __restrict__ b4,
    const float* __restrict__ w5, const float* __restrict__ b5,
    const float* __restrict__ w6, const float* __restrict__ b6,
    float* __restrict__ out) {
    const int lane = threadIdx.x & 63;
    const int col  = lane & 15;   // pair-in-tile (B/D col)
    const int g    = lane >> 4;   // k-group
    const int wid  = blockIdx.x * 4 + (threadIdx.x >> 6);
    const int nwaves = gridDim.x * 4;

    // ---- loop-invariant A-operands: transposed weights as f16 fragments ----
    FragU A2[2][2];  // [t out-tile][kt k-tile], w2: [64][32]
#pragma unroll
    for (int t = 0; t < 2; t++)
#pragma unroll
        for (int kt = 0; kt < 2; kt++)
#pragma unroll
            for (int j = 0; j < 4; j++) {
                int k = kt * 32 + g * 8 + 2 * j;
                A2[t][kt].h[j] = pkrtz(w2[k * 32 + t * 16 + col],
                                       w2[(k + 1) * 32 + t * 16 + col]);
            }
    FragU A3[2];  // w3: [32][32]
#pragma unroll
    for (int t = 0; t < 2; t++)
#pragma unroll
        for (int j = 0; j < 4; j++) {
            int k = g * 8 + 2 * j;
            A3[t].h[j] = pkrtz(w3[k * 32 + t * 16 + col],
                               w3[(k + 1) * 32 + t * 16 + col]);
        }
    FragU A4;  // w4: [32][16]
#pragma unroll
    for (int j = 0; j < 4; j++) {
        int k = g * 8 + 2 * j;
        A4.h[j] = pkrtz(w4[k * 16 + col], w4[(k + 1) * 16 + col]);
    }
    FragU A5;  // w5: [16][8]; rows(out)>=8 and k>=16 zero-padded
#pragma unroll
    for (int j = 0; j < 4; j++) {
        int k = g * 8 + 2 * j;
        if (g < 2 && col < 8)
            A5.h[j] = pkrtz(w5[k * 8 + col], w5[(k + 1) * 8 + col]);
        else
            A5.u[j] = 0;
    }
    // ---- biases per lane: out-feature = t*16 + 4g + r ----
    float bias2[8], bias3[8], bias4[4], bias5[4], w6r[4];
#pragma unroll
    for (int t = 0; t < 2; t++)
#pragma unroll
        for (int r = 0; r < 4; r++) {
            bias2[t * 4 + r] = b2[t * 16 + g * 4 + r];
            bias3[t * 4 + r] = b3[t * 16 + g * 4 + r];
        }
#pragma unroll
    for (int r = 0; r < 4; r++) {
        bias4[r] = b4[g * 4 + r];
        bias5[r] = (g < 2) ? b5[g * 4 + r] : 0.f;
        w6r[r]   = (g < 2) ? w6[g * 4 + r] : 0.f;
    }
    float b6v = b6[0];
    const vf4 z = {0.f, 0.f, 0.f, 0.f};

    for (int tile = wid; tile < NTILE; tile += nwaves) {
        int p = tile * 16 + col;
        int2 rd = ((const int2*)coo)[p];
        const float4* pr = (const float4*)(u1 + (size_t)rd.x * 64);
        const float4* pd = (const float4*)(u2 + (size_t)rd.y * 64);
        // entry: B = a1^T fragments, features g*8..g*8+7 (+32 for kt=1)
        FragU B0, B1;
        {
            float4 a = pr[2 * g],     b = pd[2 * g];
            float4 c = pr[2 * g + 1], d = pd[2 * g + 1];
            B0.h[0] = pkrtz(fmaxf(a.x + b.x, 0.f), fmaxf(a.y + b.y, 0.f));
            B0.h[1] = pkrtz(fmaxf(a.z + b.z, 0.f), fmaxf(a.w + b.w, 0.f));
            B0.h[2] = pkrtz(fmaxf(c.x + d.x, 0.f), fmaxf(c.y + d.y, 0.f));
            B0.h[3] = pkrtz(fmaxf(c.z + d.z, 0.f), fmaxf(c.w + d.w, 0.f));
            a = pr[8 + 2 * g];     b = pd[8 + 2 * g];
            c = pr[8 + 2 * g + 1]; d = pd[8 + 2 * g + 1];
            B1.h[0] = pkrtz(fmaxf(a.x + b.x, 0.f), fmaxf(a.y + b.y, 0.f));
            B1.h[1] = pkrtz(fmaxf(a.z + b.z, 0.f), fmaxf(a.w + b.w, 0.f));
            B1.h[2] = pkrtz(fmaxf(c.x + d.x, 0.f), fmaxf(c.y + d.y, 0.f));
            B1.h[3] = pkrtz(fmaxf(c.z + d.z, 0.f), fmaxf(c.w + d.w, 0.f));
        }
        // layer 2 (64 -> 32): 2 out-tiles x 2 k-tiles
        vf4 acc0 = mfma16(A2[0][0], B0, z);
        acc0 = mfma16(A2[0][1], B1, acc0);
        vf4 acc1 = mfma16(A2[1][0], B0, z);
        acc1 = mfma16(A2[1][1], B1, acc1);
#pragma unroll
        for (int r = 0; r < 4; r++) {
            acc0[r] = fmaxf(acc0[r] + bias2[r], 0.f);
            acc1[r] = fmaxf(acc1[r] + bias2[4 + r], 0.f);
        }
        // layer 3 (32 -> 32)
        FragU Bx = trans32(acc0, acc1, col, g);
        acc0 = mfma16(A3[0], Bx, z);
        acc1 = mfma16(A3[1], Bx, z);
#pragma unroll
        for (int r = 0; r < 4; r++) {
            acc0[r] = fmaxf(acc0[r] + bias3[r], 0.f);
            acc1[r] = fmaxf(acc1[r] + bias3[4 + r], 0.f);
        }
        // layer 4 (32 -> 16)
        Bx = trans32(acc0, acc1, col, g);
        vf4 a4 = mfma16(A4, Bx, z);
#pragma unroll
        for (int r = 0; r < 4; r++) a4[r] = fmaxf(a4[r] + bias4[r], 0.f);
        // layer 5 (16 -> 8, padded to 16x32)
        Bx = trans16(a4, col, g);
        vf4 a5 = mfma16(A5, Bx, z);
        // layer 6 (8 -> 1) + sigmoid on VALU
        float part = 0.f;
#pragma unroll
        for (int r = 0; r < 4; r++)
            part = fmaf(fmaxf(a5[r] + bias5[r], 0.f), w6r[r], part);
        part += __shfl_xor(part, 16);
        float sig = 1.f / (1.f + __expf(-(part + b6v)));
        if (g == 0) out[tile * 16 + col] = sig;
    }
}

// ---------------- launch ----------------
extern "C" void kernel_launch(void* const* d_in, const int* in_sizes, int n_in,
                              void* d_out, int out_size, void* d_ws, size_t ws_size,
                              hipStream_t stream) {
    const float* x    = (const float*)d_in[0];
    const int*   adj  = (const int*)d_in[1];
    const int*   coo  = (const int*)d_in[2];
    const float* gw0  = (const float*)d_in[3];
    const float* gas0 = (const float*)d_in[4];
    const float* gad0 = (const float*)d_in[5];
    const float* gb0  = (const float*)d_in[6];
    const float* gw1  = (const float*)d_in[7];
    const float* gas1 = (const float*)d_in[8];
    const float* gad1 = (const float*)d_in[9];
    const float* gb1  = (const float*)d_in[10];

    char* ws = (char*)d_ws;
    size_t o = 0;
    auto take = [&](size_t bytes) -> void* {
        void* p = ws + o;
        o = (o + bytes + 255) & ~(size_t)255;
        return p;
    };
    float* hP   = (float*)take((size_t)NNODE * RDIM * 4);
    float* hO1  = (float*)take((size_t)NNODE * RDIM * 4);
    float* hO2  = (float*)take((size_t)NNODE * RDIM * 4);
    float* u1   = (float*)take((size_t)N_RNA * 64 * 4);
    float* u2   = (float*)take((size_t)N_DIS * 64 * 4);
    float* ssrc = (float*)take((size_t)NNODE * 4);
    float* sdst = (float*)take((size_t)NNODE * 4);
    int*   offs = (int*)take((size_t)(NNODE + 1) * 4);
    int*   cnt  = (int*)take((size_t)NNODE * 4);
    int*   cur  = (int*)take((size_t)NNODE * 4);
    int*   srcs = (int*)take((size_t)NET * 4);

    hipMemsetAsync(cnt, 0, (size_t)NNODE * 4, stream);
    hipMemsetAsync(cur, 0, (size_t)NNODE * 4, stream);

    count_edges<<<(NET + 255) / 256, 256, 0, stream>>>(adj, cnt);
    scan_counts<<<1, 256, 0, stream>>>(cnt, offs);
    fill_csr<<<(NET + 255) / 256, 256, 0, stream>>>(adj, offs, cur, srcs);

    // GAT layer 1
    proj_kernel<NFDIM><<<NNODE, 64, 0, stream>>>(x, gw0, gas0, gad0, hP, ssrc, sdst);
    agg_kernel<<<NNODE, 64, 0, stream>>>(hP, ssrc, sdst, offs, srcs, gb0, hO1);
    // GAT layer 2
    proj_kernel<RDIM><<<NNODE, 64, 0, stream>>>(hO1, gw1, gas1, gad1, hP, ssrc, sdst);
    agg_kernel<<<NNODE, 64, 0, stream>>>(hP, ssrc, sdst, offs, srcs, gb1, hO2);

    // layer-1 precompute: u1 (rna nodes, +b1 folded), u2 (dis nodes)
    pair_pre_kernel<<<N_RNA + N_DIS, 64, 0, stream>>>(
        hO2, (const float*)d_in[11], (const float*)d_in[12], u1, u2);

    // pairwise MLP: f16 MFMA transposed chain
    mlp_mfma_kernel<<<1024, 256, 0, stream>>>(
        u1, u2, coo,
        (const float*)d_in[13], (const float*)d_in[14],
        (const float*)d_in[15], (const float*)d_in[16],
        (const float*)d_in[17], (const float*)d_in[18],
        (const float*)d_in[19], (const float*)d_in[20],
        (const float*)d_in[21], (const float*)d_in[22],
        (float*)d_out);
}

// Round 6
// 132.137 us; speedup vs baseline: 2.1052x; 1.0095x over previous
//
#include <hip/hip_runtime.h>
#include <cstdint>

#define N_RNA 4000
#define N_DIS 2000
#define NNODE 6016
#define NFDIM 128
#define RDIM 64
#define NE 300000
#define NET (NE + NNODE)
#define NPAIR 500000
#define NTILE (NPAIR / 16)  // 31250 exactly

typedef float vf4 __attribute__((ext_vector_type(4)));
typedef _Float16 f16x8 __attribute__((ext_vector_type(8)));
typedef _Float16 f16x2 __attribute__((ext_vector_type(2)));

union FragU {
    f16x8 f;
    f16x2 h[4];
    int   u[4];
};

__device__ __forceinline__ f16x2 pkrtz(float lo, float hi) {
    auto r = __builtin_amdgcn_cvt_pkrtz(lo, hi);
    return __builtin_bit_cast(f16x2, r);
}
__device__ __forceinline__ vf4 mfma16(const FragU& a, const FragU& b, vf4 c) {
    return __builtin_amdgcn_mfma_f32_16x16x32_f16(a.f, b.f, c, 0, 0, 0);
}

// Rebuild B-fragment (next layer's a^T) from two C/D acc tiles, in-register.
__device__ __forceinline__ FragU trans32(vf4 a0, vf4 a1, int col, int g) {
    FragU w;
    w.h[0] = pkrtz(a0[0], a0[1]);
    w.h[1] = pkrtz(a0[2], a0[3]);
    w.h[2] = pkrtz(a1[0], a1[1]);
    w.h[3] = pkrtz(a1[2], a1[3]);
    int addrA = (col + 16 * ((2 * g) & 3)) * 4;
    int addrB = (col + 16 * ((2 * g + 1) & 3)) * 4;
    int t0a = __builtin_amdgcn_ds_bpermute(addrA, w.u[0]);
    int t1a = __builtin_amdgcn_ds_bpermute(addrA, w.u[1]);
    int t2a = __builtin_amdgcn_ds_bpermute(addrA, w.u[2]);
    int t3a = __builtin_amdgcn_ds_bpermute(addrA, w.u[3]);
    int t0b = __builtin_amdgcn_ds_bpermute(addrB, w.u[0]);
    int t1b = __builtin_amdgcn_ds_bpermute(addrB, w.u[1]);
    int t2b = __builtin_amdgcn_ds_bpermute(addrB, w.u[2]);
    int t3b = __builtin_amdgcn_ds_bpermute(addrB, w.u[3]);
    bool hi = g >= 2;
    FragU B;
    B.u[0] = hi ? t2a : t0a;
    B.u[1] = hi ? t3a : t1a;
    B.u[2] = hi ? t2b : t0b;
    B.u[3] = hi ? t3b : t1b;
    return B;
}

// 16-feature source (single acc tile) -> K=32 fragment zero-padded for k>=16.
__device__ __forceinline__ FragU trans16(vf4 a, int col, int g) {
    int w0, w1;
    {
        f16x2 p0 = pkrtz(a[0], a[1]);
        f16x2 p1 = pkrtz(a[2], a[3]);
        FragU tmp; tmp.h[0] = p0; tmp.h[1] = p1;
        w0 = tmp.u[0]; w1 = tmp.u[1];
    }
    int addrA = (col + 16 * ((2 * g) & 3)) * 4;
    int addrB = (col + 16 * ((2 * g + 1) & 3)) * 4;
    int j0 = __builtin_amdgcn_ds_bpermute(addrA, w0);
    int j1 = __builtin_amdgcn_ds_bpermute(addrA, w1);
    int j2 = __builtin_amdgcn_ds_bpermute(addrB, w0);
    int j3 = __builtin_amdgcn_ds_bpermute(addrB, w1);
    bool lo2 = g < 2;
    FragU B;
    B.u[0] = lo2 ? j0 : 0;
    B.u[1] = lo2 ? j1 : 0;
    B.u[2] = lo2 ? j2 : 0;
    B.u[3] = lo2 ? j3 : 0;
    return B;
}

// ---------------- CSR build ----------------
__global__ void init_cnt(int* __restrict__ cnt, int* __restrict__ cur) {
    int i = blockIdx.x * blockDim.x + threadIdx.x;
    if (i < NNODE) { cnt[i] = 0; cur[i] = 0; }
}

__global__ void count_edges(const int* __restrict__ adj, int* __restrict__ cnt) {
    int k = blockIdx.x * blockDim.x + threadIdx.x;
    if (k >= NET) return;
    int dst = (k < NE) ? adj[NE + k] : (k - NE);
    atomicAdd(&cnt[dst], 1);
}

__global__ __launch_bounds__(256) void scan_counts(const int* __restrict__ cnt,
                                                   int* __restrict__ offs) {
    __shared__ int part[256];
    const int C = 24;  // 256*24 = 6144 >= 6016
    int t = threadIdx.x;
    int base = t * C;
    int loc[C];
    int sum = 0;
#pragma unroll
    for (int i = 0; i < C; i++) {
        int idx = base + i;
        int v = (idx < NNODE) ? cnt[idx] : 0;
        loc[i] = sum;
        sum += v;
    }
    part[t] = sum;
    __syncthreads();
    for (int off = 1; off < 256; off <<= 1) {
        int v = (t >= off) ? part[t - off] : 0;
        __syncthreads();
        part[t] += v;
        __syncthreads();
    }
    int ebase = part[t] - sum;
#pragma unroll
    for (int i = 0; i < C; i++) {
        int idx = base + i;
        if (idx < NNODE) offs[idx] = ebase + loc[i];
    }
    if (t == 255) offs[NNODE] = part[255];
}

__global__ void fill_csr(const int* __restrict__ adj, const int* __restrict__ offs,
                         int* __restrict__ cur, int* __restrict__ srcs) {
    int k = blockIdx.x * blockDim.x + threadIdx.x;
    if (k >= NET) return;
    int src, dst;
    if (k < NE) { src = adj[k]; dst = adj[NE + k]; }
    else        { src = k - NE; dst = k - NE; }
    int pos = atomicAdd(&cur[dst], 1);
    srcs[offs[dst] + pos] = src;
}

// ---------------- GAT projection: h = x @ W, plus attention scores ----------------
template <int NF>
__global__ __launch_bounds__(64) void proj_kernel(const float* __restrict__ x,
                                                  const float* __restrict__ W,
                                                  const float* __restrict__ a_s,
                                                  const float* __restrict__ a_d,
                                                  float* __restrict__ h,
                                                  float* __restrict__ ssrc,
                                                  float* __restrict__ sdst) {
    __shared__ float xr[NF];
    int node = blockIdx.x;
    int t = threadIdx.x;
    {
        const float* xp = x + (size_t)node * NF;
        for (int i = t; i < NF; i += 64) xr[i] = xp[i];
    }
    __syncthreads();
    float acc = 0.f;
#pragma unroll 8
    for (int k = 0; k < NF; k++) acc = fmaf(xr[k], W[k * RDIM + t], acc);
    h[(size_t)node * RDIM + t] = acc;
    float vs = acc * a_s[t];
    float vd = acc * a_d[t];
#pragma unroll
    for (int off = 32; off; off >>= 1) {
        vs += __shfl_down(vs, off);
        vd += __shfl_down(vd, off);
    }
    if (t == 0) { ssrc[node] = vs; sdst[node] = vd; }
}

// ---------------- GAT aggregation v2: 4 edge-groups x 16 lanes x float4 ----------------
__global__ __launch_bounds__(64) void agg_kernel(const float* __restrict__ h,
                                                 const float* __restrict__ ssrc,
                                                 const float* __restrict__ sdst,
                                                 const int* __restrict__ offs,
                                                 const int* __restrict__ srcs,
                                                 const float* __restrict__ bias,
                                                 float* __restrict__ out) {
    int node = blockIdx.x;
    int t = threadIdx.x;
    int beg = offs[node], end = offs[node + 1];
    float sd = sdst[node];
    // pass 1: segment max, 64 lanes over edges
    float m = -1e30f;
    for (int i = beg + t; i < end; i += 64) {
        float v = ssrc[srcs[i]] + sd;
        v = v > 0.f ? v : 0.2f * v;
        m = fmaxf(m, v);
    }
#pragma unroll
    for (int off = 32; off; off >>= 1) m = fmaxf(m, __shfl_xor(m, off));
    // pass 2: 4 edges in parallel; 16 lanes x float4 cover the 64 features
    int g = t >> 4, q = t & 15;
    float ax = 0.f, ay = 0.f, az = 0.f, aw = 0.f, den = 0.f;
    for (int i = beg + g; i < end; i += 4) {
        int s = srcs[i];
        float v = ssrc[s] + sd;
        v = v > 0.f ? v : 0.2f * v;
        float ex = __expf(v - m);
        den += ex;
        float4 hv = *(const float4*)(h + (size_t)s * 64 + q * 4);
        ax = fmaf(ex, hv.x, ax);
        ay = fmaf(ex, hv.y, ay);
        az = fmaf(ex, hv.z, az);
        aw = fmaf(ex, hv.w, aw);
    }
#pragma unroll
    for (int off = 16; off <= 32; off <<= 1) {
        ax += __shfl_xor(ax, off);
        ay += __shfl_xor(ay, off);
        az += __shfl_xor(az, off);
        aw += __shfl_xor(aw, off);
        den += __shfl_xor(den, off);
    }
    if (t < 16) {
        float inv = 1.f / den;
        float4 b4 = ((const float4*)bias)[q];
        float4 o;
        o.x = ax * inv + b4.x;
        o.y = ay * inv + b4.y;
        o.z = az * inv + b4.z;
        o.w = aw * inv + b4.w;
        *(float4*)(out + (size_t)node * 64 + q * 4) = o;
    }
}

// ---------------- pair-independent layer-1 precompute ----------------
__global__ __launch_bounds__(64) void pair_pre_kernel(const float* __restrict__ h,
                                                      const float* __restrict__ w1,
                                                      const float* __restrict__ b1,
                                                      float* __restrict__ u1,
                                                      float* __restrict__ u2) {
    __shared__ float xr[64];
    int node = blockIdx.x;
    int t = threadIdx.x;
    bool rna = node < N_RNA;
    xr[t] = h[(size_t)node * RDIM + t];
    __syncthreads();
    const float* w = rna ? w1 : (w1 + 64 * 64);
    float acc = rna ? b1[t] : 0.f;
#pragma unroll
    for (int k = 0; k < 64; k++) acc = fmaf(xr[k], w[k * 64 + t], acc);
    if (rna) u1[(size_t)node * 64 + t] = acc;
    else     u2[(size_t)(node - N_RNA) * 64 + t] = acc;
}

// ---------------- pairwise MLP: f16 MFMA transposed chain ----------------
__global__ __launch_bounds__(256) void mlp_mfma_kernel(
    const float* __restrict__ u1, const float* __restrict__ u2,
    const int* __restrict__ coo,
    const float* __restrict__ w2, const float* __restrict__ b2,
    const float* __restrict__ w3, const float* __restrict__ b3,
    const float* __restrict__ w4, const float* __restrict__ b4,
    const float* __restrict__ w5, const float* __restrict__ b5,
    const float* __restrict__ w6, const float* __restrict__ b6,
    float* __restrict__ out) {
    const int lane = threadIdx.x & 63;
    const int col  = lane & 15;   // pair-in-tile (B/D col)
    const int g    = lane >> 4;   // k-group
    const int wid  = blockIdx.x * 4 + (threadIdx.x >> 6);
    const int nwaves = gridDim.x * 4;

    // ---- loop-invariant A-operands: transposed weights as f16 fragments ----
    FragU A2[2][2];  // [t out-tile][kt k-tile], w2: [64][32]
#pragma unroll
    for (int t = 0; t < 2; t++)
#pragma unroll
        for (int kt = 0; kt < 2; kt++)
#pragma unroll
            for (int j = 0; j < 4; j++) {
                int k = kt * 32 + g * 8 + 2 * j;
                A2[t][kt].h[j] = pkrtz(w2[k * 32 + t * 16 + col],
                                       w2[(k + 1) * 32 + t * 16 + col]);
            }
    FragU A3[2];  // w3: [32][32]
#pragma unroll
    for (int t = 0; t < 2; t++)
#pragma unroll
        for (int j = 0; j < 4; j++) {
            int k = g * 8 + 2 * j;
            A3[t].h[j] = pkrtz(w3[k * 32 + t * 16 + col],
                               w3[(k + 1) * 32 + t * 16 + col]);
        }
    FragU A4;  // w4: [32][16]
#pragma unroll
    for (int j = 0; j < 4; j++) {
        int k = g * 8 + 2 * j;
        A4.h[j] = pkrtz(w4[k * 16 + col], w4[(k + 1) * 16 + col]);
    }
    FragU A5;  // w5: [16][8]; rows(out)>=8 and k>=16 zero-padded
#pragma unroll
    for (int j = 0; j < 4; j++) {
        int k = g * 8 + 2 * j;
        if (g < 2 && col < 8)
            A5.h[j] = pkrtz(w5[k * 8 + col], w5[(k + 1) * 8 + col]);
        else
            A5.u[j] = 0;
    }
    // ---- biases per lane: out-feature = t*16 + 4g + r ----
    float bias2[8], bias3[8], bias4[4], bias5[4], w6r[4];
#pragma unroll
    for (int t = 0; t < 2; t++)
#pragma unroll
        for (int r = 0; r < 4; r++) {
            bias2[t * 4 + r] = b2[t * 16 + g * 4 + r];
            bias3[t * 4 + r] = b3[t * 16 + g * 4 + r];
        }
#pragma unroll
    for (int r = 0; r < 4; r++) {
        bias4[r] = b4[g * 4 + r];
        bias5[r] = (g < 2) ? b5[g * 4 + r] : 0.f;
        w6r[r]   = (g < 2) ? w6[g * 4 + r] : 0.f;
    }
    float b6v = b6[0];
    const vf4 z = {0.f, 0.f, 0.f, 0.f};

    for (int tile = wid; tile < NTILE; tile += nwaves) {
        int p = tile * 16 + col;
        int2 rd = ((const int2*)coo)[p];
        const float4* pr = (const float4*)(u1 + (size_t)rd.x * 64);
        const float4* pd = (const float4*)(u2 + (size_t)rd.y * 64);
        // entry: B = a1^T fragments, features g*8..g*8+7 (+32 for kt=1)
        FragU B0, B1;
        {
            float4 a = pr[2 * g],     b = pd[2 * g];
            float4 c = pr[2 * g + 1], d = pd[2 * g + 1];
            B0.h[0] = pkrtz(fmaxf(a.x + b.x, 0.f), fmaxf(a.y + b.y, 0.f));
            B0.h[1] = pkrtz(fmaxf(a.z + b.z, 0.f), fmaxf(a.w + b.w, 0.f));
            B0.h[2] = pkrtz(fmaxf(c.x + d.x, 0.f), fmaxf(c.y + d.y, 0.f));
            B0.h[3] = pkrtz(fmaxf(c.z + d.z, 0.f), fmaxf(c.w + d.w, 0.f));
            a = pr[8 + 2 * g];     b = pd[8 + 2 * g];
            c = pr[8 + 2 * g + 1]; d = pd[8 + 2 * g + 1];
            B1.h[0] = pkrtz(fmaxf(a.x + b.x, 0.f), fmaxf(a.y + b.y, 0.f));
            B1.h[1] = pkrtz(fmaxf(a.z + b.z, 0.f), fmaxf(a.w + b.w, 0.f));
            B1.h[2] = pkrtz(fmaxf(c.x + d.x, 0.f), fmaxf(c.y + d.y, 0.f));
            B1.h[3] = pkrtz(fmaxf(c.z + d.z, 0.f), fmaxf(c.w + d.w, 0.f));
        }
        // layer 2 (64 -> 32): 2 out-tiles x 2 k-tiles
        vf4 acc0 = mfma16(A2[0][0], B0, z);
        acc0 = mfma16(A2[0][1], B1, acc0);
        vf4 acc1 = mfma16(A2[1][0], B0, z);
        acc1 = mfma16(A2[1][1], B1, acc1);
#pragma unroll
        for (int r = 0; r < 4; r++) {
            acc0[r] = fmaxf(acc0[r] + bias2[r], 0.f);
            acc1[r] = fmaxf(acc1[r] + bias2[4 + r], 0.f);
        }
        // layer 3 (32 -> 32)
        FragU Bx = trans32(acc0, acc1, col, g);
        acc0 = mfma16(A3[0], Bx, z);
        acc1 = mfma16(A3[1], Bx, z);
#pragma unroll
        for (int r = 0; r < 4; r++) {
            acc0[r] = fmaxf(acc0[r] + bias3[r], 0.f);
            acc1[r] = fmaxf(acc1[r] + bias3[4 + r], 0.f);
        }
        // layer 4 (32 -> 16)
        Bx = trans32(acc0, acc1, col, g);
        vf4 a4 = mfma16(A4, Bx, z);
#pragma unroll
        for (int r = 0; r < 4; r++) a4[r] = fmaxf(a4[r] + bias4[r], 0.f);
        // layer 5 (16 -> 8, padded to 16x32)
        Bx = trans16(a4, col, g);
        vf4 a5 = mfma16(A5, Bx, z);
        // layer 6 (8 -> 1) + sigmoid on VALU
        float part = 0.f;
#pragma unroll
        for (int r = 0; r < 4; r++)
            part = fmaf(fmaxf(a5[r] + bias5[r], 0.f), w6r[r], part);
        part += __shfl_xor(part, 16);
        float sig = 1.f / (1.f + __expf(-(part + b6v)));
        if (g == 0) out[tile * 16 + col] = sig;
    }
}

// ---------------- launch ----------------
extern "C" void kernel_launch(void* const* d_in, const int* in_sizes, int n_in,
                              void* d_out, int out_size, void* d_ws, size_t ws_size,
                              hipStream_t stream) {
    const float* x    = (const float*)d_in[0];
    const int*   adj  = (const int*)d_in[1];
    const int*   coo  = (const int*)d_in[2];
    const float* gw0  = (const float*)d_in[3];
    const float* gas0 = (const float*)d_in[4];
    const float* gad0 = (const float*)d_in[5];
    const float* gb0  = (const float*)d_in[6];
    const float* gw1  = (const float*)d_in[7];
    const float* gas1 = (const float*)d_in[8];
    const float* gad1 = (const float*)d_in[9];
    const float* gb1  = (const float*)d_in[10];

    char* ws = (char*)d_ws;
    size_t o = 0;
    auto take = [&](size_t bytes) -> void* {
        void* p = ws + o;
        o = (o + bytes + 255) & ~(size_t)255;
        return p;
    };
    float* hP   = (float*)take((size_t)NNODE * RDIM * 4);
    float* hO1  = (float*)take((size_t)NNODE * RDIM * 4);
    float* hO2  = (float*)take((size_t)NNODE * RDIM * 4);
    float* u1   = (float*)take((size_t)N_RNA * 64 * 4);
    float* u2   = (float*)take((size_t)N_DIS * 64 * 4);
    float* ssrc = (float*)take((size_t)NNODE * 4);
    float* sdst = (float*)take((size_t)NNODE * 4);
    int*   offs = (int*)take((size_t)(NNODE + 1) * 4);
    int*   cnt  = (int*)take((size_t)NNODE * 4);
    int*   cur  = (int*)take((size_t)NNODE * 4);
    int*   srcs = (int*)take((size_t)NET * 4);

    init_cnt<<<(NNODE + 255) / 256, 256, 0, stream>>>(cnt, cur);
    count_edges<<<(NET + 255) / 256, 256, 0, stream>>>(adj, cnt);
    scan_counts<<<1, 256, 0, stream>>>(cnt, offs);
    fill_csr<<<(NET + 255) / 256, 256, 0, stream>>>(adj, offs, cur, srcs);

    // GAT layer 1
    proj_kernel<NFDIM><<<NNODE, 64, 0, stream>>>(x, gw0, gas0, gad0, hP, ssrc, sdst);
    agg_kernel<<<NNODE, 64, 0, stream>>>(hP, ssrc, sdst, offs, srcs, gb0, hO1);
    // GAT layer 2
    proj_kernel<RDIM><<<NNODE, 64, 0, stream>>>(hO1, gw1, gas1, gad1, hP, ssrc, sdst);
    agg_kernel<<<NNODE, 64, 0, stream>>>(hP, ssrc, sdst, offs, srcs, gb1, hO2);

    // layer-1 precompute: u1 (rna nodes, +b1 folded), u2 (dis nodes)
    pair_pre_kernel<<<N_RNA + N_DIS, 64, 0, stream>>>(
        hO2, (const float*)d_in[11], (const float*)d_in[12], u1, u2);

    // pairwise MLP: f16 MFMA transposed chain
    mlp_mfma_kernel<<<1024, 256, 0, stream>>>(
        u1, u2, coo,
        (const float*)d_in[13], (const float*)d_in[14],
        (const float*)d_in[15], (const float*)d_in[16],
        (const float*)d_in[17], (const float*)d_in[18],
        (const float*)d_in[19], (const float*)d_in[20],
        (const float*)d_in[21], (const float*)d_in[22],
        (float*)d_out);
}